// Round 3
// baseline (1916.868 us; speedup 1.0000x reference)
//
#include <hip/hip_runtime.h>
#include <hip/hip_bf16.h>

#define DM 2048   // d_model
#define DF 1408   // d_ff
#define NE 6      // experts
#define NB 8      // batch
#define NS 4096   // seq

typedef __bf16 bf16x8 __attribute__((ext_vector_type(8)));
typedef float f32x4 __attribute__((ext_vector_type(4)));

__device__ __forceinline__ void gload_lds16(const void* g, void* l) {
  __builtin_amdgcn_global_load_lds(
      (const __attribute__((address_space(1))) void*)g,
      (__attribute__((address_space(3))) void*)l, 16, 0, 0);
}

// ---------------- mean over sequence (partial sums + atomics) ----------------
__global__ void mean_kernel(const float* __restrict__ x, float* __restrict__ xsum) {
  int idx = blockIdx.x * 256 + threadIdx.x;   // 0 .. NB*DM-1
  int b = idx >> 11;                          // / 2048
  int d = idx & (DM - 1);
  int s0 = blockIdx.y * (NS / 16);
  const float* p = x + (size_t)b * NS * DM + (size_t)s0 * DM + d;
  float sum = 0.f;
  for (int s = 0; s < NS / 16; ++s) sum += p[(size_t)s * DM];
  atomicAdd(&xsum[idx], sum);
}

// ---------------- gating: logits, softmax, top-2, renormalize ----------------
__global__ void gate_kernel(const float* __restrict__ xsum, const float* __restrict__ gate_W,
                            int* __restrict__ gsel, float* __restrict__ gw) {
  __shared__ float logits[NB][NE];
  int t = threadIdx.x;
  if (t < NB * NE) {
    int b = t / NE, e = t % NE;
    const float* xm = xsum + b * DM;
    const float* gv = gate_W + e * DM;
    float s = 0.f;
    for (int i = 0; i < DM; ++i) s += xm[i] * gv[i];
    logits[b][e] = s * (1.0f / NS);
  }
  __syncthreads();
  if (t < NB) {
    int e0 = 0; float l0 = logits[t][0];
    for (int e = 1; e < NE; ++e) if (logits[t][e] > l0) { l0 = logits[t][e]; e0 = e; }
    int e1 = -1; float l1 = -1e30f;
    for (int e = 0; e < NE; ++e) if (e != e0 && logits[t][e] > l1) { l1 = logits[t][e]; e1 = e; }
    float z = expf(l1 - l0);            // <= 1
    float w0 = 1.f / (1.f + z);
    gsel[2 * t] = e0; gsel[2 * t + 1] = e1;
    gw[2 * t] = w0;   gw[2 * t + 1] = 1.f - w0;
  }
}

// ---------------- x f32 -> bf16 (vectorized) ----------------
__global__ void convert_x_kernel(const float4* __restrict__ in, ushort4* __restrict__ outp, int n4) {
  int stride = gridDim.x * blockDim.x;
  for (int i = blockIdx.x * blockDim.x + threadIdx.x; i < n4; i += stride) {
    float4 v = in[i];
    union { ushort4 u; __hip_bfloat16 h[4]; } pk;
    pk.h[0] = __float2bfloat16(v.x);
    pk.h[1] = __float2bfloat16(v.y);
    pk.h[2] = __float2bfloat16(v.z);
    pk.h[3] = __float2bfloat16(v.w);
    outp[i] = pk.u;
  }
}

// ---------------- transpose + convert: in [E][R][C] f32 -> out [E][C][R] bf16 ----------------
__global__ void transpose_conv_kernel(const float* __restrict__ in, __hip_bfloat16* __restrict__ out,
                                      int R, int C) {
  __shared__ float tile[32][33];
  int e = blockIdx.z;
  int c0 = blockIdx.x * 32, r0 = blockIdx.y * 32;
  int tx = threadIdx.x & 31, ty = threadIdx.x >> 5;   // 32 x 8
  const float* src = in + (size_t)e * R * C;
  __hip_bfloat16* dst = out + (size_t)e * C * R;
#pragma unroll
  for (int i = 0; i < 4; ++i)
    tile[ty + 8 * i][tx] = src[(size_t)(r0 + ty + 8 * i) * C + (c0 + tx)];
  __syncthreads();
#pragma unroll
  for (int i = 0; i < 4; ++i)
    dst[(size_t)(c0 + ty + 8 * i) * R + (r0 + tx)] = __float2bfloat16(tile[tx][ty + 8 * i]);
}

// ---------------- GEMM1: H[slot] = wk * gelu(x[b] @ W1[e] + b1[e])  (bf16 out) ----------------
__global__ __launch_bounds__(256) void gemm1_kernel(
    const short* __restrict__ Xb,     // [NB][NS][DM] bf16
    const short* __restrict__ W1T,    // [NE][DF][DM] bf16
    const float* __restrict__ b1,     // [NE][DF]
    __hip_bfloat16* __restrict__ H,   // [slots][NS][DF]
    const int* __restrict__ gsel, const float* __restrict__ gw, int pair_base) {
  const int slot = blockIdx.z;
  const int p = pair_base + slot;
  const int b = p >> 1;
  const int e = gsel[p];
  const float wk = gw[p];
  const short* Ag = Xb + (size_t)b * NS * DM;
  const short* Bg = W1T + (size_t)e * DF * DM;

  const int m0 = blockIdx.y * 128;
  const int n0 = blockIdx.x * 128;
  const int lane = threadIdx.x & 63;
  const int wid = threadIdx.x >> 6;
  const int wr = wid >> 1, wc = wid & 1;

  __shared__ __align__(16) short As[128 * 64];
  __shared__ __align__(16) short Bs[128 * 64];

  f32x4 acc[4][4] = {};
  const int rsub = lane >> 3;
  const int cbyte = (lane & 7) * 16;

  for (int k0 = 0; k0 < DM; k0 += 64) {
#pragma unroll
    for (int i = 0; i < 4; ++i) {
      const int chunk = wid * 4 + i;
      gload_lds16((const char*)Ag + ((size_t)(m0 + chunk * 8 + rsub) * DM + k0) * 2 + cbyte,
                  (char*)As + chunk * 1024);
      gload_lds16((const char*)Bg + ((size_t)(n0 + chunk * 8 + rsub) * DM + k0) * 2 + cbyte,
                  (char*)Bs + chunk * 1024);
    }
    __syncthreads();
#pragma unroll
    for (int kk = 0; kk < 2; ++kk) {
      const int ko = kk * 32 + (lane >> 4) * 8;
      bf16x8 af[4], bfv[4];
#pragma unroll
      for (int mi = 0; mi < 4; ++mi)
        af[mi] = *reinterpret_cast<const bf16x8*>(&As[(wr * 64 + mi * 16 + (lane & 15)) * 64 + ko]);
#pragma unroll
      for (int ni = 0; ni < 4; ++ni)
        bfv[ni] = *reinterpret_cast<const bf16x8*>(&Bs[(wc * 64 + ni * 16 + (lane & 15)) * 64 + ko]);
#pragma unroll
      for (int mi = 0; mi < 4; ++mi)
#pragma unroll
        for (int ni = 0; ni < 4; ++ni)
          acc[mi][ni] = __builtin_amdgcn_mfma_f32_16x16x32_bf16(af[mi], bfv[ni], acc[mi][ni], 0, 0, 0);
    }
    __syncthreads();
  }

  __hip_bfloat16* Hout = H + (size_t)slot * NS * DF;
#pragma unroll
  for (int ni = 0; ni < 4; ++ni) {
    const int col = n0 + wc * 64 + ni * 16 + (lane & 15);
    const float bias = b1[e * DF + col];
#pragma unroll
    for (int mi = 0; mi < 4; ++mi) {
      const int rbase = m0 + wr * 64 + mi * 16 + ((lane >> 4) << 2);
#pragma unroll
      for (int j = 0; j < 4; ++j) {
        float v = acc[mi][ni][j] + bias;
        v = 0.5f * v * (1.0f + erff(v * 0.70710678118654752f));   // exact-erf gelu
        Hout[(size_t)(rbase + j) * DF + col] = __float2bfloat16(v * wk);
      }
    }
  }
}

// ---------------- GEMM2: out[b] = sum_k H[b,k] @ W2[e_k] + blended bias (f32 out) ----------------
__global__ __launch_bounds__(256) void gemm2_kernel(
    const short* __restrict__ Hbuf,   // [slots][NS][DF] bf16
    const short* __restrict__ W2T,    // [NE][DM][DF] bf16
    const float* __restrict__ b2,     // [NE][DM]
    float* __restrict__ outp,         // [NB][NS][DM]
    const int* __restrict__ gsel, const float* __restrict__ gw, int b_base) {
  const int b = b_base + blockIdx.z;
  const int e0 = gsel[2 * b], e1 = gsel[2 * b + 1];
  const float w0 = gw[2 * b], w1 = gw[2 * b + 1];

  const int m0 = blockIdx.y * 128;
  const int n0 = blockIdx.x * 128;
  const int lane = threadIdx.x & 63;
  const int wid = threadIdx.x >> 6;
  const int wr = wid >> 1, wc = wid & 1;

  __shared__ __align__(16) short As[128 * 64];
  __shared__ __align__(16) short Bs[128 * 64];

  f32x4 acc[4][4] = {};
  const int rsub = lane >> 3;
  const int cbyte = (lane & 7) * 16;

  for (int ks = 0; ks < 2; ++ks) {
    const short* Ag = Hbuf + (size_t)(blockIdx.z * 2 + ks) * NS * DF;
    const short* Bg = W2T + (size_t)gsel[2 * b + ks] * DM * DF;
    for (int k0 = 0; k0 < DF; k0 += 64) {
#pragma unroll
      for (int i = 0; i < 4; ++i) {
        const int chunk = wid * 4 + i;
        gload_lds16((const char*)Ag + ((size_t)(m0 + chunk * 8 + rsub) * DF + k0) * 2 + cbyte,
                    (char*)As + chunk * 1024);
        gload_lds16((const char*)Bg + ((size_t)(n0 + chunk * 8 + rsub) * DF + k0) * 2 + cbyte,
                    (char*)Bs + chunk * 1024);
      }
      __syncthreads();
#pragma unroll
      for (int kk = 0; kk < 2; ++kk) {
        const int ko = kk * 32 + (lane >> 4) * 8;
        bf16x8 af[4], bfv[4];
#pragma unroll
        for (int mi = 0; mi < 4; ++mi)
          af[mi] = *reinterpret_cast<const bf16x8*>(&As[(wr * 64 + mi * 16 + (lane & 15)) * 64 + ko]);
#pragma unroll
        for (int ni = 0; ni < 4; ++ni)
          bfv[ni] = *reinterpret_cast<const bf16x8*>(&Bs[(wc * 64 + ni * 16 + (lane & 15)) * 64 + ko]);
#pragma unroll
        for (int mi = 0; mi < 4; ++mi)
#pragma unroll
          for (int ni = 0; ni < 4; ++ni)
            acc[mi][ni] = __builtin_amdgcn_mfma_f32_16x16x32_bf16(af[mi], bfv[ni], acc[mi][ni], 0, 0, 0);
      }
      __syncthreads();
    }
  }

  float* Og = outp + (size_t)b * NS * DM;
#pragma unroll
  for (int ni = 0; ni < 4; ++ni) {
    const int col = n0 + wc * 64 + ni * 16 + (lane & 15);
    const float bias = w0 * b2[e0 * DM + col] + w1 * b2[e1 * DM + col];
#pragma unroll
    for (int mi = 0; mi < 4; ++mi) {
      const int rbase = m0 + wr * 64 + mi * 16 + ((lane >> 4) << 2);
#pragma unroll
      for (int j = 0; j < 4; ++j)
        Og[(size_t)(rbase + j) * DM + col] = acc[mi][ni][j] + bias;
    }
  }
}

extern "C" void kernel_launch(void* const* d_in, const int* in_sizes, int n_in,
                              void* d_out, int out_size, void* d_ws, size_t ws_size,
                              hipStream_t stream) {
  const float* x      = (const float*)d_in[0];
  const float* gate_W = (const float*)d_in[1];
  const float* W1     = (const float*)d_in[2];
  const float* b1     = (const float*)d_in[3];
  const float* W2     = (const float*)d_in[4];
  const float* b2     = (const float*)d_in[5];
  float* outp = (float*)d_out;

  char* ws = (char*)d_ws;
  size_t off = 0;
  auto alloc = [&](size_t bytes) { size_t o = off; off += (bytes + 255) & ~(size_t)255; return o; };
  size_t xmean_off = alloc((size_t)NB * DM * 4);
  size_t gsel_off  = alloc(16 * 4);
  size_t gw_off    = alloc(16 * 4);
  size_t xb_off    = alloc((size_t)NB * NS * DM * 2);
  size_t w1t_off   = alloc((size_t)NE * DF * DM * 2);
  size_t w2t_off   = alloc((size_t)NE * DM * DF * 2);
  size_t h_off     = off;
  size_t h_full    = (size_t)16 * NS * DF * 2;
  bool full = (h_off + h_full) <= ws_size;

  float* xsum = (float*)(ws + xmean_off);
  int*   gsel = (int*)(ws + gsel_off);
  float* gw   = (float*)(ws + gw_off);
  short* xb   = (short*)(ws + xb_off);
  short* w1t  = (short*)(ws + w1t_off);
  short* w2t  = (short*)(ws + w2t_off);
  __hip_bfloat16* Hbuf = (__hip_bfloat16*)(ws + h_off);

  hipMemsetAsync(xsum, 0, (size_t)NB * DM * 4, stream);
  mean_kernel<<<dim3(NB * DM / 256, 16), 256, 0, stream>>>(x, xsum);
  gate_kernel<<<1, 64, 0, stream>>>(xsum, gate_W, gsel, gw);
  convert_x_kernel<<<2048, 256, 0, stream>>>((const float4*)x, (ushort4*)xb, NB * NS * DM / 4);
  transpose_conv_kernel<<<dim3(DF / 32, DM / 32, NE), 256, 0, stream>>>(W1, (__hip_bfloat16*)w1t, DM, DF);
  transpose_conv_kernel<<<dim3(DM / 32, DF / 32, NE), 256, 0, stream>>>(W2, (__hip_bfloat16*)w2t, DF, DM);

  if (full) {
    gemm1_kernel<<<dim3(DF / 128, NS / 128, 16), 256, 0, stream>>>(
        xb, w1t, b1, Hbuf, gsel, gw, 0);
    gemm2_kernel<<<dim3(DM / 128, NS / 128, NB), 256, 0, stream>>>(
        (const short*)Hbuf, w2t, b2, outp, gsel, gw, 0);
  } else {
    for (int b = 0; b < NB; ++b) {
      gemm1_kernel<<<dim3(DF / 128, NS / 128, 2), 256, 0, stream>>>(
          xb, w1t, b1, Hbuf, gsel, gw, 2 * b);
      gemm2_kernel<<<dim3(DM / 128, NS / 128, 1), 256, 0, stream>>>(
          (const short*)Hbuf, w2t, b2, outp, gsel, gw, b);
    }
  }
}